// Round 3
// baseline (1072.030 us; speedup 1.0000x reference)
//
#include <hip/hip_runtime.h>
#include <hip/hip_bf16.h>

#define VOCAB 2048
#define EMBD  256
#define LATD  64
#define TLEN  32
#define BATCH 64
#define NBLK  256

typedef __attribute__((ext_vector_type(8))) short bf16x8;
typedef __attribute__((ext_vector_type(4))) float f32x4;

// ---------------- init: out=1.5, h[0]=0, barrier counters=0 ----------------
__global__ void k_init(float* __restrict__ out, ushort* __restrict__ h0,
                       unsigned* __restrict__ bar) {
  int i = blockIdx.x * 256 + threadIdx.x;   // grid 512*256 = 131072
  out[i] = 1.5f;     // 64*32*64
  h0[i]  = 0;        // 64*2048 bf16 (parity 0)
  if (i < TLEN) bar[i] = 0;
}

// ---------- transpose+convert: src[K][8192] f32 -> dst[8192][K] bf16 ----------
__global__ void k_transpose(const float* __restrict__ src,
                            __hip_bfloat16* __restrict__ dst, int K) {
  __shared__ __hip_bfloat16 tile[64][72];
  int k0 = (blockIdx.x >> 7) * 64;
  int n0 = (blockIdx.x & 127) * 64;
  int tid = threadIdx.x;
  {
    int kl = tid >> 2;
    int nq = (tid & 3) << 4;
    const float* s = src + (size_t)(k0 + kl) * 8192 + n0 + nq;
#pragma unroll
    for (int i = 0; i < 4; ++i) {
      float4 v = *reinterpret_cast<const float4*>(s + i * 4);
      tile[nq + i * 4 + 0][kl] = __float2bfloat16(v.x);
      tile[nq + i * 4 + 1][kl] = __float2bfloat16(v.y);
      tile[nq + i * 4 + 2][kl] = __float2bfloat16(v.z);
      tile[nq + i * 4 + 3][kl] = __float2bfloat16(v.w);
    }
  }
  __syncthreads();
  {
    int nl = tid >> 2;
    int kq = (tid & 3) << 4;
    uint4* d = reinterpret_cast<uint4*>(dst + (size_t)(n0 + nl) * K + k0 + kq);
    const uint4* s = reinterpret_cast<const uint4*>(&tile[nl][kq]);
    d[0] = s[0];
    d[1] = s[1];
  }
}

// ---------- gather: xb[t*64+b][256] = bf16(emb[tokens[b][t]]) ----------
__global__ void k_gather(const int* __restrict__ tokens,
                         const float* __restrict__ emb,
                         __hip_bfloat16* __restrict__ xb) {
  int tid = threadIdx.x;
  int row = blockIdx.x * 4 + (tid >> 6);   // 512 blocks -> 2048 rows
  int lane = tid & 63;
  int t = row >> 6, b = row & 63;
  int tok = tokens[b * TLEN + t];
  float4 v = *reinterpret_cast<const float4*>(emb + (size_t)tok * EMBD + lane * 4);
  __hip_bfloat16* d = xb + (size_t)row * EMBD + lane * 4;
  d[0] = __float2bfloat16(v.x);
  d[1] = __float2bfloat16(v.y);
  d[2] = __float2bfloat16(v.z);
  d[3] = __float2bfloat16(v.w);
}

// One-shot grid barrier (counter used exactly once per step; k_init re-zeroes
// each launch). __syncthreads drains vmcnt for all waves -> block stores are
// in L2; thread0's agent fence writes back / invalidates L2 for cross-XCD
// visibility of h/stats (per-XCD L2s are non-coherent).
__device__ __forceinline__ void grid_barrier(unsigned* cnt) {
  __syncthreads();
  if (threadIdx.x == 0) {
    __threadfence();  // release: L2 writeback
    __hip_atomic_fetch_add(cnt, 1u, __ATOMIC_RELAXED, __HIP_MEMORY_SCOPE_AGENT);
    while (__hip_atomic_load(cnt, __ATOMIC_RELAXED, __HIP_MEMORY_SCOPE_AGENT) < NBLK)
      __builtin_amdgcn_s_sleep(2);
    __threadfence();  // acquire: L2 invalidate
  }
  __syncthreads();
}

// ---------------- persistent kernel: all 32 steps ----------------
// grid 256 blocks x 512 threads, 1 block/CU (all co-resident). Block j owns
// vocab cols v = j*8..j*8+7 (z-cols gate*2048 + j*8 + vc). 8 waves split K.
// Wh/Wx B-fragments live in VGPRs for the whole kernel (72 VGPRs/wave);
// c lives in registers (2 f32/thread). Grid barrier between steps.
__global__ __launch_bounds__(512, 1) void k_step(
    const int* __restrict__ tokens,
    const __hip_bfloat16* __restrict__ WhT,   // [8192][2048]
    const __hip_bfloat16* __restrict__ WxT,   // [8192][256]
    const __hip_bfloat16* __restrict__ xb,    // [2048][256] row = t*64+b
    const float* __restrict__ bias,           // [8192]
    __hip_bfloat16* __restrict__ hbuf,        // [2][64][2048]
    float* __restrict__ stats,                // [2][3][64][256]
    float* __restrict__ out,                  // [64][32][64]
    unsigned* __restrict__ bar) {             // [32]
  const int tid = threadIdx.x;
  const int lane = tid & 63;
  const int wid = tid >> 6;                  // 0..7
  const int j = blockIdx.x;

  __shared__ float racc[8][4][2][4][64];   // [wid][mf][nf][r][lane] 64KB
  __shared__ float sred[24];
  __shared__ float svalS;

  const int rr = lane & 15;
  const int kg = lane >> 4;                 // 0..3 (K groups of 8)
  const int gcol0 = ((rr >> 3) << 11) + (j << 3) + (rr & 7);          // cols 0..15
  const int gcol1 = (((16 + rr) >> 3) << 11) + (j << 3) + (rr & 7);   // cols 16..31

  // ---- preload B fragments into registers (loop-invariant) ----
  bf16x8 B0[9], B1[9];
#pragma unroll
  for (int it = 0; it < 8; ++it) {
    int kb = (wid + 8 * (it >> 1)) * 64 + (it & 1) * 32 + kg * 8;
    B0[it] = *(const bf16x8*)(WhT + (size_t)gcol0 * VOCAB + kb);
    B1[it] = *(const bf16x8*)(WhT + (size_t)gcol1 * VOCAB + kb);
  }
  {
    int kbx = wid * 32 + kg * 8;
    B0[8] = *(const bf16x8*)(WxT + (size_t)gcol0 * EMBD + kbx);
    B1[8] = *(const bf16x8*)(WxT + (size_t)gcol1 * EMBD + kbx);
  }

  // ---- epilogue constants; c in registers ----
  const int m = wid >> 1;                  // fragment 0..3
  const int half = wid & 1;                // r in {2*half, 2*half+1}
  const int s_ = (lane >> 3) & 1;
  const int vc = lane & 7;
  const int v = (j << 3) + vc;
  const float bias0 = bias[s_ * 2048 + v];        // frag0 gate: i (s=0) / f (s=1)
  const float bias1 = bias[(2 + s_) * 2048 + v];  // frag1 gate: g (s=0) / o (s=1)
  float c_reg[2] = {0.f, 0.f};

  for (int t = 0; t < TLEN; ++t) {
    const int par = t & 1;
    const __hip_bfloat16* hcur = hbuf + par * (BATCH * VOCAB);
    __hip_bfloat16* hnext = hbuf + (par ^ 1) * (BATCH * VOCAB);

    // ---- bounds output for step t (stats of h_t written last step) ----
    if (j < BATCH) {
      float val;
      if (t == 0) {
        int tok = tokens[j * TLEN];
        val = 1.5f * (2.f * tok + 1.f) * (1.f / 2048.f);
      } else {
        const float* st = stats + par * 3 * BATCH * NBLK;
        float a0 = 0.f, a1 = 0.f, a2 = 0.f;
        if (tid < NBLK) {
          a0 = st[(0 * BATCH + j) * NBLK + tid];
          a1 = st[(1 * BATCH + j) * NBLK + tid];
          a2 = st[(2 * BATCH + j) * NBLK + tid];
        }
#pragma unroll
        for (int off = 32; off; off >>= 1) {
          a0 += __shfl_down(a0, off);
          a1 += __shfl_down(a1, off);
          a2 += __shfl_down(a2, off);
        }
        if (lane == 0) { sred[wid * 3] = a0; sred[wid * 3 + 1] = a1; sred[wid * 3 + 2] = a2; }
        __syncthreads();
        if (tid == 0) {
          float S = 0.f, SL = 0.f, ST = 0.f;
#pragma unroll
          for (int w = 0; w < 4; ++w) {     // waves 4..7 loaded zeros
            S  += sred[w * 3];
            SL += sred[w * 3 + 1];
            ST += sred[w * 3 + 2];
          }
          svalS = 1.5f * (2.f * SL + ST) / S;
        }
        __syncthreads();
        val = svalS;
      }
      if (tid >= t && tid < TLEN) out[(j * TLEN + tid) * LATD + t] = val;
    }

    // ---- GEMM: z[64 x 32cols] over K=2304, 8 waves split K, B in regs ----
    f32x4 acc[4][2];
#pragma unroll
    for (int mf = 0; mf < 4; ++mf)
#pragma unroll
      for (int nf = 0; nf < 2; ++nf) acc[mf][nf] = (f32x4){0.f, 0.f, 0.f, 0.f};

#pragma unroll
    for (int it = 0; it < 9; ++it) {
      bf16x8 a0, a1, a2, a3;
      if (it < 8) {
        int kb = (wid + 8 * (it >> 1)) * 64 + (it & 1) * 32 + kg * 8;
        const __hip_bfloat16* p = hcur + kb;
        a0 = *(const bf16x8*)(p + (0 * 16 + rr) * VOCAB);
        a1 = *(const bf16x8*)(p + (1 * 16 + rr) * VOCAB);
        a2 = *(const bf16x8*)(p + (2 * 16 + rr) * VOCAB);
        a3 = *(const bf16x8*)(p + (3 * 16 + rr) * VOCAB);
      } else {
        int kbx = wid * 32 + kg * 8;
        const __hip_bfloat16* p = xb + (size_t)t * BATCH * EMBD + kbx;
        a0 = *(const bf16x8*)(p + (0 * 16 + rr) * EMBD);
        a1 = *(const bf16x8*)(p + (1 * 16 + rr) * EMBD);
        a2 = *(const bf16x8*)(p + (2 * 16 + rr) * EMBD);
        a3 = *(const bf16x8*)(p + (3 * 16 + rr) * EMBD);
      }
      acc[0][0] = __builtin_amdgcn_mfma_f32_16x16x32_bf16(a0, B0[it], acc[0][0], 0, 0, 0);
      acc[0][1] = __builtin_amdgcn_mfma_f32_16x16x32_bf16(a0, B1[it], acc[0][1], 0, 0, 0);
      acc[1][0] = __builtin_amdgcn_mfma_f32_16x16x32_bf16(a1, B0[it], acc[1][0], 0, 0, 0);
      acc[1][1] = __builtin_amdgcn_mfma_f32_16x16x32_bf16(a1, B1[it], acc[1][1], 0, 0, 0);
      acc[2][0] = __builtin_amdgcn_mfma_f32_16x16x32_bf16(a2, B0[it], acc[2][0], 0, 0, 0);
      acc[2][1] = __builtin_amdgcn_mfma_f32_16x16x32_bf16(a2, B1[it], acc[2][1], 0, 0, 0);
      acc[3][0] = __builtin_amdgcn_mfma_f32_16x16x32_bf16(a3, B0[it], acc[3][0], 0, 0, 0);
      acc[3][1] = __builtin_amdgcn_mfma_f32_16x16x32_bf16(a3, B1[it], acc[3][1], 0, 0, 0);
    }

    // ---- cross-wave K reduction ----
#pragma unroll
    for (int mf = 0; mf < 4; ++mf)
#pragma unroll
      for (int nf = 0; nf < 2; ++nf)
#pragma unroll
        for (int r = 0; r < 4; ++r) racc[wid][mf][nf][r][lane] = acc[mf][nf][r];
    __syncthreads();

    // ---- epilogue: wave pair (2m,2m+1) finishes fragment m; half splits r ----
    const int tnext = (t + 1 < TLEN) ? t + 1 : TLEN - 1;
    float e_[2], sl_[2], st_[2];
#pragma unroll
    for (int r2 = 0; r2 < 2; ++r2) {
      int r = half * 2 + r2;
      int row = m * 16 + kg * 4 + r;
      float z0 = bias0, z1 = bias1;
#pragma unroll
      for (int w = 0; w < 8; ++w) {
        z0 += racc[w][m][0][r][lane];
        z1 += racc[w][m][1][r][lane];
      }
      float o0 = __shfl_xor(z0, 8);
      float o1 = __shfl_xor(z1, 8);
      float zi = s_ ? o0 : z0;
      float zf = s_ ? z0 : o0;
      float zg = s_ ? o1 : z1;
      float zo = s_ ? z1 : o1;
      float cold = c_reg[r2];
      float gi = 1.f / (1.f + __expf(-zi));
      float gf = 1.f / (1.f + __expf(-zf));
      float go = 1.f / (1.f + __expf(-zo));
      float cnew = gf * cold + gi * tanhf(zg);
      float hn = go * tanhf(cnew);
      c_reg[r2] = cnew;
      if (!s_) hnext[row * VOCAB + v] = __float2bfloat16(hn);
      float e = __expf(hn);
      int tok = tokens[row * TLEN + tnext];
      e_[r2] = e;
      sl_[r2] = (v < tok) ? e : 0.f;
      st_[r2] = (v == tok) ? e : 0.f;
    }
#pragma unroll
    for (int mm = 1; mm <= 4; mm <<= 1)
#pragma unroll
      for (int r2 = 0; r2 < 2; ++r2) {
        e_[r2] += __shfl_xor(e_[r2], mm);
        sl_[r2] += __shfl_xor(sl_[r2], mm);
        st_[r2] += __shfl_xor(st_[r2], mm);
      }
    if (vc == 0 && s_ == 0) {
      float* stn = stats + (par ^ 1) * 3 * BATCH * NBLK;
#pragma unroll
      for (int r2 = 0; r2 < 2; ++r2) {
        int row = m * 16 + kg * 4 + half * 2 + r2;
        stn[(0 * BATCH + row) * NBLK + j] = e_[r2];
        stn[(1 * BATCH + row) * NBLK + j] = sl_[r2];
        stn[(2 * BATCH + row) * NBLK + j] = st_[r2];
      }
    }

    // ---- step boundary: make h/stats visible to all XCDs ----
    if (t < TLEN - 1) grid_barrier(&bar[t]);
  }
}

extern "C" void kernel_launch(void* const* d_in, const int* in_sizes, int n_in,
                              void* d_out, int out_size, void* d_ws, size_t ws_size,
                              hipStream_t stream) {
  (void)in_sizes; (void)n_in; (void)out_size; (void)ws_size;
  const int* tokens = (const int*)d_in[0];
  const float* emb  = (const float*)d_in[1];
  const float* Wx   = (const float*)d_in[2];
  const float* Wh   = (const float*)d_in[3];
  const float* bias = (const float*)d_in[4];
  float* out = (float*)d_out;
  char* ws = (char*)d_ws;

  __hip_bfloat16* WhT = (__hip_bfloat16*)(ws);               // 33,554,432 B
  __hip_bfloat16* WxT = (__hip_bfloat16*)(ws + 33554432);    //  4,194,304 B
  __hip_bfloat16* xb  = (__hip_bfloat16*)(ws + 37748736);    //  1,048,576 B
  __hip_bfloat16* hb  = (__hip_bfloat16*)(ws + 38797312);    //    524,288 B
  float* stats        = (float*)(ws + 39321600);             //    393,216 B
  unsigned* bar       = (unsigned*)(ws + 39714816);          //        128 B

  k_init<<<512, 256, 0, stream>>>(out, (ushort*)hb, bar);
  k_transpose<<<4096, 256, 0, stream>>>(Wh, WhT, 2048);
  k_transpose<<<512, 256, 0, stream>>>(Wx, WxT, 256);
  k_gather<<<512, 256, 0, stream>>>(tokens, emb, xb);
  k_step<<<NBLK, 512, 0, stream>>>(tokens, WhT, WxT, xb, bias, hb, stats, out, bar);
}

// Round 4
// 542.362 us; speedup vs baseline: 1.9766x; 1.9766x over previous
//
#include <hip/hip_runtime.h>
#include <hip/hip_bf16.h>

#define VOCAB 2048
#define EMBD  256
#define LATD  64
#define TLEN  32
#define BATCH 64
#define NBLK  256

typedef __attribute__((ext_vector_type(8))) short bf16x8;
typedef __attribute__((ext_vector_type(4))) float f32x4;

// ---------------- init: out=1.5, c=0, h[0]=0 ----------------
__global__ void k_init(float* __restrict__ out, float* __restrict__ c,
                       ushort* __restrict__ h0) {
  int i = blockIdx.x * 256 + threadIdx.x;   // grid 512*256 = 131072
  out[i] = 1.5f;     // 64*32*64
  c[i]   = 0.f;      // 64*2048
  h0[i]  = 0;        // 64*2048 bf16 (parity 0)
}

// ---------- transpose+convert: src[K][8192] f32 -> dst[8192][K] bf16 ----------
__global__ void k_transpose(const float* __restrict__ src,
                            __hip_bfloat16* __restrict__ dst, int K) {
  __shared__ __hip_bfloat16 tile[64][72];
  int k0 = (blockIdx.x >> 7) * 64;
  int n0 = (blockIdx.x & 127) * 64;
  int tid = threadIdx.x;
  {
    int kl = tid >> 2;
    int nq = (tid & 3) << 4;
    const float* s = src + (size_t)(k0 + kl) * 8192 + n0 + nq;
#pragma unroll
    for (int i = 0; i < 4; ++i) {
      float4 v = *reinterpret_cast<const float4*>(s + i * 4);
      tile[nq + i * 4 + 0][kl] = __float2bfloat16(v.x);
      tile[nq + i * 4 + 1][kl] = __float2bfloat16(v.y);
      tile[nq + i * 4 + 2][kl] = __float2bfloat16(v.z);
      tile[nq + i * 4 + 3][kl] = __float2bfloat16(v.w);
    }
  }
  __syncthreads();
  {
    int nl = tid >> 2;
    int kq = (tid & 3) << 4;
    uint4* d = reinterpret_cast<uint4*>(dst + (size_t)(n0 + nl) * K + k0 + kq);
    const uint4* s = reinterpret_cast<const uint4*>(&tile[nl][kq]);
    d[0] = s[0];
    d[1] = s[1];
  }
}

// ---------- gather: xb[t*64+b][256] = bf16(emb[tokens[b][t]]) ----------
__global__ void k_gather(const int* __restrict__ tokens,
                         const float* __restrict__ emb,
                         __hip_bfloat16* __restrict__ xb) {
  int tid = threadIdx.x;
  int row = blockIdx.x * 4 + (tid >> 6);   // 512 blocks -> 2048 rows
  int lane = tid & 63;
  int t = row >> 6, b = row & 63;
  int tok = tokens[b * TLEN + t];
  float4 v = *reinterpret_cast<const float4*>(emb + (size_t)tok * EMBD + lane * 4);
  __hip_bfloat16* d = xb + (size_t)row * EMBD + lane * 4;
  d[0] = __float2bfloat16(v.x);
  d[1] = __float2bfloat16(v.y);
  d[2] = __float2bfloat16(v.z);
  d[3] = __float2bfloat16(v.w);
}

// ---------------- one recurrence step ----------------
// grid 256 x 512 threads (8 waves, 2/SIMD). Block j owns vocab cols
// v = j*8..j*8+7 (z-cols gate*2048 + j*8 + vc). 8 waves split K=2304.
// K-loop software-pipelined with a depth-6 register ring (fully unrolled,
// compile-time ring indices) -> ~36 loads in flight, ~1 L2/L3 round trip.
// Output phase runs entirely in wave 0 (no block barrier before the GEMM).
__global__ __launch_bounds__(512, 2) void k_step(
    const int* __restrict__ tokens,
    const __hip_bfloat16* __restrict__ WhT,   // [8192][2048]
    const __hip_bfloat16* __restrict__ WxT,   // [8192][256]
    const __hip_bfloat16* __restrict__ xb,    // [2048][256] row = t*64+b
    const float* __restrict__ bias,           // [8192]
    __hip_bfloat16* __restrict__ hbuf,        // [2][64][2048]
    float* __restrict__ cbuf,                 // [64][2048]
    float* __restrict__ stats,                // [2][3][64][256]
    float* __restrict__ out,                  // [64][32][64]
    int t) {
  const int tid = threadIdx.x;
  const int lane = tid & 63;
  const int wid = tid >> 6;                  // 0..7
  const int j = blockIdx.x;
  const int par = t & 1;
  const __hip_bfloat16* hcur = hbuf + par * (BATCH * VOCAB);
  __hip_bfloat16* hnext = hbuf + (par ^ 1) * (BATCH * VOCAB);

  __shared__ float racc[8][4][2][4][64];   // [wid][mf][nf][r][lane] 64KB

  const int rr = lane & 15;
  const int kg = lane >> 4;                 // 0..3 (K groups of 8)
  const int gcol0 = ((rr >> 3) << 11) + (j << 3) + (rr & 7);          // cols 0..15
  const int gcol1 = (((16 + rr) >> 3) << 11) + (j << 3) + (rr & 7);   // cols 16..31

  // ---- epilogue constants, hoisted loads (latency hides under GEMM) ----
  const int m = wid >> 1;                  // fragment 0..3
  const int half = wid & 1;                // r in {2*half, 2*half+1}
  const int s_ = (lane >> 3) & 1;
  const int vc = lane & 7;
  const int v = (j << 3) + vc;
  const float bias0 = bias[s_ * 2048 + v];        // frag0 gate: i (s=0) / f (s=1)
  const float bias1 = bias[(2 + s_) * 2048 + v];  // frag1 gate: g (s=0) / o (s=1)
  const int tnext = (t + 1 < TLEN) ? t + 1 : TLEN - 1;
  const int row0 = m * 16 + kg * 4 + half * 2;
  const int row1 = row0 + 1;
  const float cold0 = cbuf[row0 * VOCAB + v];
  const float cold1 = cbuf[row1 * VOCAB + v];
  const int tok0 = tokens[row0 * TLEN + tnext];
  const int tok1 = tokens[row1 * TLEN + tnext];

  // ---- output phase: wave 0 only, no block barrier ----
  if (j < BATCH && wid == 0) {
    float val;
    if (t == 0) {
      int tok = tokens[j * TLEN];
      val = 1.5f * (2.f * tok + 1.f) * (1.f / 2048.f);
    } else {
      const float* st = stats + par * 3 * BATCH * NBLK;
      float4 u0 = *reinterpret_cast<const float4*>(st + (0 * BATCH + j) * NBLK + lane * 4);
      float4 u1 = *reinterpret_cast<const float4*>(st + (1 * BATCH + j) * NBLK + lane * 4);
      float4 u2 = *reinterpret_cast<const float4*>(st + (2 * BATCH + j) * NBLK + lane * 4);
      float a0 = u0.x + u0.y + u0.z + u0.w;
      float a1 = u1.x + u1.y + u1.z + u1.w;
      float a2 = u2.x + u2.y + u2.z + u2.w;
#pragma unroll
      for (int mm = 1; mm <= 32; mm <<= 1) {
        a0 += __shfl_xor(a0, mm);
        a1 += __shfl_xor(a1, mm);
        a2 += __shfl_xor(a2, mm);
      }
      val = 1.5f * (2.f * a1 + a2) / a0;
    }
    if (lane >= t && lane < TLEN) out[(j * TLEN + lane) * LATD + t] = val;
  }

  // ---- GEMM: z[64 x 32cols] over K=2304, 8 waves split K ----
  f32x4 acc[4][2];
#pragma unroll
  for (int mf = 0; mf < 4; ++mf)
#pragma unroll
    for (int nf = 0; nf < 2; ++nf) acc[mf][nf] = (f32x4){0.f, 0.f, 0.f, 0.f};

  bf16x8 Ar[6][4];
  bf16x8 Br[6][2];
  auto issue = [&](int it) {
    int slot = it % 6;
    if (it < 8) {
      int kb = (wid + 8 * (it >> 1)) * 64 + (it & 1) * 32 + kg * 8;
      const __hip_bfloat16* p = hcur + kb;
      Ar[slot][0] = *(const bf16x8*)(p + (0 * 16 + rr) * VOCAB);
      Ar[slot][1] = *(const bf16x8*)(p + (1 * 16 + rr) * VOCAB);
      Ar[slot][2] = *(const bf16x8*)(p + (2 * 16 + rr) * VOCAB);
      Ar[slot][3] = *(const bf16x8*)(p + (3 * 16 + rr) * VOCAB);
      Br[slot][0] = *(const bf16x8*)(WhT + (size_t)gcol0 * VOCAB + kb);
      Br[slot][1] = *(const bf16x8*)(WhT + (size_t)gcol1 * VOCAB + kb);
    } else {
      int kbx = wid * 32 + kg * 8;
      const __hip_bfloat16* p = xb + (size_t)t * BATCH * EMBD + kbx;
      Ar[slot][0] = *(const bf16x8*)(p + (0 * 16 + rr) * EMBD);
      Ar[slot][1] = *(const bf16x8*)(p + (1 * 16 + rr) * EMBD);
      Ar[slot][2] = *(const bf16x8*)(p + (2 * 16 + rr) * EMBD);
      Ar[slot][3] = *(const bf16x8*)(p + (3 * 16 + rr) * EMBD);
      Br[slot][0] = *(const bf16x8*)(WxT + (size_t)gcol0 * EMBD + kbx);
      Br[slot][1] = *(const bf16x8*)(WxT + (size_t)gcol1 * EMBD + kbx);
    }
  };

#pragma unroll
  for (int it = 0; it < 6; ++it) issue(it);
#pragma unroll
  for (int it = 0; it < 9; ++it) {
    const int sl = it % 6;
    acc[0][0] = __builtin_amdgcn_mfma_f32_16x16x32_bf16(Ar[sl][0], Br[sl][0], acc[0][0], 0, 0, 0);
    acc[0][1] = __builtin_amdgcn_mfma_f32_16x16x32_bf16(Ar[sl][0], Br[sl][1], acc[0][1], 0, 0, 0);
    acc[1][0] = __builtin_amdgcn_mfma_f32_16x16x32_bf16(Ar[sl][1], Br[sl][0], acc[1][0], 0, 0, 0);
    acc[1][1] = __builtin_amdgcn_mfma_f32_16x16x32_bf16(Ar[sl][1], Br[sl][1], acc[1][1], 0, 0, 0);
    acc[2][0] = __builtin_amdgcn_mfma_f32_16x16x32_bf16(Ar[sl][2], Br[sl][0], acc[2][0], 0, 0, 0);
    acc[2][1] = __builtin_amdgcn_mfma_f32_16x16x32_bf16(Ar[sl][2], Br[sl][1], acc[2][1], 0, 0, 0);
    acc[3][0] = __builtin_amdgcn_mfma_f32_16x16x32_bf16(Ar[sl][3], Br[sl][0], acc[3][0], 0, 0, 0);
    acc[3][1] = __builtin_amdgcn_mfma_f32_16x16x32_bf16(Ar[sl][3], Br[sl][1], acc[3][1], 0, 0, 0);
    if (it + 6 < 9) issue(it + 6);
  }

  // ---- cross-wave K reduction ----
#pragma unroll
  for (int mf = 0; mf < 4; ++mf)
#pragma unroll
    for (int nf = 0; nf < 2; ++nf)
#pragma unroll
      for (int r = 0; r < 4; ++r) racc[wid][mf][nf][r][lane] = acc[mf][nf][r];
  __syncthreads();

  // ---- epilogue: wave pair (2m,2m+1) finishes fragment m; half splits r ----
  float e_[2], sl_[2], st_[2];
#pragma unroll
  for (int r2 = 0; r2 < 2; ++r2) {
    int r = half * 2 + r2;
    int row = r2 ? row1 : row0;
    float z0 = bias0, z1 = bias1;
#pragma unroll
    for (int w = 0; w < 8; ++w) {
      z0 += racc[w][m][0][r][lane];
      z1 += racc[w][m][1][r][lane];
    }
    float o0 = __shfl_xor(z0, 8);
    float o1 = __shfl_xor(z1, 8);
    float zi = s_ ? o0 : z0;
    float zf = s_ ? z0 : o0;
    float zg = s_ ? o1 : z1;
    float zo = s_ ? z1 : o1;
    float cold = r2 ? cold1 : cold0;
    float gi = 1.f / (1.f + __expf(-zi));
    float gf = 1.f / (1.f + __expf(-zf));
    float go = 1.f / (1.f + __expf(-zo));
    float cnew = gf * cold + gi * tanhf(zg);
    float hn = go * tanhf(cnew);
    if (!s_) {
      cbuf[row * VOCAB + v] = cnew;
      hnext[row * VOCAB + v] = __float2bfloat16(hn);
    }
    float e = __expf(hn);
    int tok = r2 ? tok1 : tok0;
    e_[r2] = e;
    sl_[r2] = (v < tok) ? e : 0.f;
    st_[r2] = (v == tok) ? e : 0.f;
  }
#pragma unroll
  for (int mm = 1; mm <= 4; mm <<= 1)
#pragma unroll
    for (int r2 = 0; r2 < 2; ++r2) {
      e_[r2] += __shfl_xor(e_[r2], mm);
      sl_[r2] += __shfl_xor(sl_[r2], mm);
      st_[r2] += __shfl_xor(st_[r2], mm);
    }
  if (vc == 0 && s_ == 0) {
    float* stn = stats + (par ^ 1) * 3 * BATCH * NBLK;
#pragma unroll
    for (int r2 = 0; r2 < 2; ++r2) {
      int row = r2 ? row1 : row0;
      stn[(0 * BATCH + row) * NBLK + j] = e_[r2];
      stn[(1 * BATCH + row) * NBLK + j] = sl_[r2];
      stn[(2 * BATCH + row) * NBLK + j] = st_[r2];
    }
  }
}

extern "C" void kernel_launch(void* const* d_in, const int* in_sizes, int n_in,
                              void* d_out, int out_size, void* d_ws, size_t ws_size,
                              hipStream_t stream) {
  (void)in_sizes; (void)n_in; (void)out_size; (void)ws_size;
  const int* tokens = (const int*)d_in[0];
  const float* emb  = (const float*)d_in[1];
  const float* Wx   = (const float*)d_in[2];
  const float* Wh   = (const float*)d_in[3];
  const float* bias = (const float*)d_in[4];
  float* out = (float*)d_out;
  char* ws = (char*)d_ws;

  __hip_bfloat16* WhT = (__hip_bfloat16*)(ws);               // 33,554,432 B
  __hip_bfloat16* WxT = (__hip_bfloat16*)(ws + 33554432);    //  4,194,304 B
  __hip_bfloat16* xb  = (__hip_bfloat16*)(ws + 37748736);    //  1,048,576 B
  __hip_bfloat16* hb  = (__hip_bfloat16*)(ws + 38797312);    //    524,288 B
  float* cb           = (float*)(ws + 39321600);             //    524,288 B
  float* stats        = (float*)(ws + 39845888);             //    393,216 B

  k_init<<<512, 256, 0, stream>>>(out, cb, (ushort*)hb);
  k_transpose<<<4096, 256, 0, stream>>>(Wh, WhT, 2048);
  k_transpose<<<512, 256, 0, stream>>>(Wx, WxT, 256);
  k_gather<<<512, 256, 0, stream>>>(tokens, emb, xb);
  for (int t = 0; t < TLEN; ++t)
    k_step<<<NBLK, 512, 0, stream>>>(tokens, WhT, WxT, xb, bias, hb, cb, stats, out, t);
}